// Round 11
// baseline (207.260 us; speedup 1.0000x reference)
//
#include <hip/hip_runtime.h>
#include <hip/hip_bf16.h>
#include <math.h>

typedef __attribute__((ext_vector_type(8))) short bf16x8;
typedef __attribute__((ext_vector_type(4))) short bf16x4;
typedef __attribute__((ext_vector_type(4))) float floatx4;

constexpr int kN  = 4096;
constexpr int kD  = 768;
constexpr int kH  = 12;
constexpr int kHD = 64;
constexpr int k3D = 2304;
// Q pre-scale: (1/sqrt(64)) * log2(e) so softmax runs in exp2 domain with no muls
constexpr float kQScale = 0.18033688011112042f;

static __device__ __forceinline__ short f2b(float f) {
    __hip_bfloat16 h = __float2bfloat16(f);
    return *reinterpret_cast<short*>(&h);
}

static __device__ __forceinline__ float fast_exp2(float x) {
#if __has_builtin(__builtin_amdgcn_exp2f)
    return __builtin_amdgcn_exp2f(x);
#else
    return exp2f(x);
#endif
}

// Async global->LDS DMA, 16B per lane. LDS dst is wave-uniform base + lane*16.
static __device__ __forceinline__ void async_copy16(const void* g, void* l) {
    __builtin_amdgcn_global_load_lds(
        (const __attribute__((address_space(1))) void*)g,
        (__attribute__((address_space(3))) void*)l, 16, 0, 0);
}

// Fused prep: section 0 = x fp32->bf16; section 1 = W_qkv transpose->bf16;
// section 2 = W_out transpose->bf16.
constexpr int kBlkX  = 1536;            // (4096*768/8)/256
constexpr int kBlkWq = 72 * 24;         // (2304/32) x (768/32)
constexpr int kBlkWo = 24 * 24;         // (768/32) x (768/32)

__global__ __launch_bounds__(256)
void prep(const float* __restrict__ x, const float* __restrict__ Wq,
          const float* __restrict__ Wo, short* __restrict__ Xb,
          short* __restrict__ WqT, short* __restrict__ WoT)
{
    const int bid = blockIdx.x;
    const int tid = threadIdx.x;
    if (bid < kBlkX) {
        const int i = bid * 256 + tid;
        const float4* s = reinterpret_cast<const float4*>(x + (size_t)i * 8);
        float4 a = s[0], b = s[1];
        bf16x8 v;
        v[0] = f2b(a.x); v[1] = f2b(a.y); v[2] = f2b(a.z); v[3] = f2b(a.w);
        v[4] = f2b(b.x); v[5] = f2b(b.y); v[6] = f2b(b.z); v[7] = f2b(b.w);
        *reinterpret_cast<bf16x8*>(Xb + (size_t)i * 8) = v;
        return;
    }
    const float* src; short* dst; int R, C, bx, by;
    if (bid < kBlkX + kBlkWq) {
        const int local = bid - kBlkX;
        src = Wq; dst = WqT; R = kD; C = k3D; bx = local % 72; by = local / 72;
    } else {
        const int local = bid - kBlkX - kBlkWq;
        src = Wo; dst = WoT; R = kD; C = kD; bx = local % 24; by = local / 24;
    }
    __shared__ float t[32][33];
    const int c0 = bx * 32, r0 = by * 32;
    const int tx = tid & 31, ty = tid >> 5;
    #pragma unroll
    for (int i = ty; i < 32; i += 8)
        t[i][tx] = src[(size_t)(r0 + i) * C + c0 + tx];
    __syncthreads();
    #pragma unroll
    for (int i = ty; i < 32; i += 8)
        dst[(size_t)(c0 + i) * R + r0 + tx] = f2b(t[tx][i]);
}

// C = A[M x K] * BT[N x K]^T, bf16 in, fp32 acc. Block tile (2*WM) x (2*WN),
// BK=32, 4 waves in a 2x2 grid (wave tile WM x WN). Smaller tiles than 128^2
// on purpose: these GEMMs are grid-starved (0.75-2.25 blocks/CU at 128^2), so
// more blocks/CU lets other blocks' compute hide each block's DMA drain.
// MODE 0: Cout fp32 = C + bias;  MODE 1: scatter bf16 Qh(*kQScale), Kh, Vt[h][d][n]
template<int WM, int WN, int MODE>
__device__ __forceinline__
void gemm_core(const short* __restrict__ A, const short* __restrict__ BT,
               const float* __restrict__ bias, float* __restrict__ Cout,
               short* __restrict__ Qh, short* __restrict__ Kh, short* __restrict__ Vt,
               int N, int K)
{
    const int bm   = blockIdx.x * (2 * WM);
    const int bn   = blockIdx.y * (2 * WN);
    const int tid  = threadIdx.x;
    const int wave = tid >> 6;
    const int lane = tid & 63;
    const int l15  = lane & 15;
    const int quad = lane >> 4;
    const int l3   = l15 & 3;

    constexpr int MT = WM / 16;
    constexpr int NT = WN / 16;

    __shared__ alignas(16) short As[2 * WM * 32];
    __shared__ alignas(16) short Bs[2 * WN * 32];

    floatx4 acc[MT][NT] = {};
    const int wm = WM * (wave >> 1);
    const int wn = WN * (wave & 1);

    const int srl = lane >> 2;               // row within 16-row issue group
    const int scc = (lane & 3) ^ (srl & 3);  // swizzled source chunk

    for (int k0 = 0; k0 < K; k0 += 32) {
        __syncthreads();
        #pragma unroll
        for (int j = 0; j < (2 * WM) / 64; ++j) {
            const int rs = ((2 * WM) / 64) * 16 * wave + 16 * j;
            async_copy16(&A[(size_t)(bm + rs + srl) * K + k0 + 8 * scc], &As[rs * 32]);
        }
        #pragma unroll
        for (int j = 0; j < (2 * WN) / 64; ++j) {
            const int rs = ((2 * WN) / 64) * 16 * wave + 16 * j;
            async_copy16(&BT[(size_t)(bn + rs + srl) * K + k0 + 8 * scc], &Bs[rs * 32]);
        }
        __syncthreads();

        bf16x8 af[MT], bfr[NT];
        #pragma unroll
        for (int mt = 0; mt < MT; ++mt)
            af[mt] = *reinterpret_cast<const bf16x8*>(&As[(wm + 16 * mt + l15) * 32 + 8 * (quad ^ l3)]);
        #pragma unroll
        for (int nt = 0; nt < NT; ++nt)
            bfr[nt] = *reinterpret_cast<const bf16x8*>(&Bs[(wn + 16 * nt + l15) * 32 + 8 * (quad ^ l3)]);
        #pragma unroll
        for (int mt = 0; mt < MT; ++mt)
            #pragma unroll
            for (int nt = 0; nt < NT; ++nt)
                acc[mt][nt] = __builtin_amdgcn_mfma_f32_16x16x32_bf16(af[mt], bfr[nt], acc[mt][nt], 0, 0, 0);
    }

    #pragma unroll
    for (int mt = 0; mt < MT; ++mt) {
        #pragma unroll
        for (int nt = 0; nt < NT; ++nt) {
            #pragma unroll
            for (int r = 0; r < 4; ++r) {
                const int row = bm + wm + mt * 16 + 4 * quad + r;
                const int col = bn + wn + nt * 16 + l15;
                float v = acc[mt][nt][r];
                if (MODE == 0) {
                    Cout[(size_t)row * N + col] = v + bias[col];
                } else {
                    const int proj   = col / kD;   // 128-col blocks never span projections
                    const int within = col - proj * kD;
                    const int h = within >> 6;
                    const int d = within & 63;
                    if (proj == 0)      Qh[((size_t)h * kN + row) * kHD + d] = f2b(v * kQScale);
                    else if (proj == 1) Kh[((size_t)h * kN + row) * kHD + d] = f2b(v);
                    else                Vt[((size_t)h * kHD + d) * kN + row] = f2b(v);
                }
            }
        }
    }
}

__global__ __launch_bounds__(256)
void gemm_qkv(const short* __restrict__ A, const short* __restrict__ BT,
              short* __restrict__ Qh, short* __restrict__ Kh, short* __restrict__ Vt)
{
    gemm_core<32, 64, 1>(A, BT, nullptr, nullptr, Qh, Kh, Vt, k3D, kD);
}

__global__ __launch_bounds__(256)
void gemm_out(const short* __restrict__ A, const short* __restrict__ BT,
              const float* __restrict__ bias, float* __restrict__ Cout)
{
    gemm_core<32, 32, 0>(A, BT, bias, Cout, nullptr, nullptr, nullptr, kD, kD);
}

// Flash attention, no-max softmax, S^T form, KV-split waves (r9 verbatim —
// known-good 94 us; r10's 80 KB dbuf exceeded the 64 KB workgroup LDS limit).
__global__ __launch_bounds__(256, 3)
void attn(const short* __restrict__ Qh, const short* __restrict__ Kh,
          const short* __restrict__ Vt, short* __restrict__ AO)
{
    const int h    = blockIdx.y;
    const int q0   = blockIdx.x * 64;
    const int tid  = threadIdx.x;
    const int wave = tid >> 6;
    const int lane = tid & 63;
    const int l15  = lane & 15;
    const int quad = lane >> 4;
    const int lx   = l15 & 7;
    const int px   = l15 & 3;                  // P swizzle mask (row & 3)

    __shared__ alignas(16) char smem[49920];
    short* Ks = (short*)smem;                  // [128][64] swizzled (16 KB)
    short* Vs = (short*)(smem + 16384);        // [64][128] swizzled (16 KB)
    short* Pm = (short*)(smem + 32768);        // 4 waves x [64 m][32 kv] (16 KB)
    float* Red  = (float*)smem;                // overlay: 3 waves x 16 tiles x 64 lanes x f4
    float* Dred = (float*)(smem + 49152);      // [3][4][16] denom partials

    short* Pw = Pm + wave * 2048;

    // Q fragments: all 64 Q rows (4 m-tiles x 2 d-chunks), B-operand layout.
    bf16x8 qf[4][2];
    #pragma unroll
    for (int mt = 0; mt < 4; ++mt) {
        const size_t qb = ((size_t)h * kN + q0 + 16 * mt + l15) * kHD + quad * 8;
        qf[mt][0] = *reinterpret_cast<const bf16x8*>(&Qh[qb]);
        qf[mt][1] = *reinterpret_cast<const bf16x8*>(&Qh[qb + 32]);
    }

    floatx4 oacc[4][4] = {};                   // [mt][dt] partial O over wave's kv
    float psum[4] = {0.f, 0.f, 0.f, 0.f};      // [mt] denom partials, row = l15

    const int krl = lane >> 3;
    const int kcc = (lane & 7) ^ (krl & 7);
    const int vrl = lane >> 4;
    const int vp  = lane & 15;

    for (int kv0 = 0; kv0 < kN; kv0 += 128) {
        __syncthreads();   // A: prior tile's K/V/P reads complete
        #pragma unroll
        for (int j = 0; j < 4; ++j) {
            const int rk = 32 * wave + 8 * j;
            async_copy16(&Kh[((size_t)h * kN + kv0 + rk + krl) * kHD + 8 * kcc],
                         &Ks[rk * 64]);
            const int rv0 = 16 * wave + 4 * j;
            const int rv  = rv0 + vrl;
            async_copy16(&Vt[((size_t)h * kHD + rv) * kN + kv0 + 8 * (vp ^ (rv & 7))],
                         &Vs[rv0 * 128]);
        }
        __syncthreads();   // B: staging visible

        // S^T = K Q^T for wave's kv rows: tiles (nt in 0..1) x (mt in 0..3)
        #pragma unroll
        for (int nt = 0; nt < 2; ++nt) {
            const int krow = (32 * wave + 16 * nt + l15) * 64;
            bf16x8 kf0 = *reinterpret_cast<const bf16x8*>(&Ks[krow + 8 * (quad ^ lx)]);
            bf16x8 kf1 = *reinterpret_cast<const bf16x8*>(&Ks[krow + 8 * ((4 + quad) ^ lx)]);
            #pragma unroll
            for (int mt = 0; mt < 4; ++mt) {
                floatx4 sa = {};
                sa = __builtin_amdgcn_mfma_f32_16x16x32_bf16(kf0, qf[mt][0], sa, 0, 0, 0);
                sa = __builtin_amdgcn_mfma_f32_16x16x32_bf16(kf1, qf[mt][1], sa, 0, 0, 0);
                const float p0 = fast_exp2(sa[0]);
                const float p1 = fast_exp2(sa[1]);
                const float p2 = fast_exp2(sa[2]);
                const float p3 = fast_exp2(sa[3]);
                psum[mt] += (p0 + p1) + (p2 + p3);
                bf16x4 pk;
                pk[0] = f2b(p0); pk[1] = f2b(p1); pk[2] = f2b(p2); pk[3] = f2b(p3);
                *reinterpret_cast<bf16x4*>(
                    &Pw[(16 * mt + l15) * 32 + 8 * ((2 * nt + (quad >> 1)) ^ px) + 4 * (quad & 1)]) = pk;
            }
        }
        // no barrier: Pw wave-private, per-wave DS ops are in-order

        // PV: A = P rows (k = wave's 32 kv), B = V^T rows (chunk 4*wave+quad)
        bf16x8 pa[4];
        #pragma unroll
        for (int mt = 0; mt < 4; ++mt)
            pa[mt] = *reinterpret_cast<const bf16x8*>(
                &Pw[(16 * mt + l15) * 32 + 8 * (quad ^ px)]);
        #pragma unroll
        for (int dt = 0; dt < 4; ++dt) {
            bf16x8 vv = *reinterpret_cast<const bf16x8*>(
                &Vs[(16 * dt + l15) * 128 + 8 * ((4 * wave + quad) ^ lx)]);
            #pragma unroll
            for (int mt = 0; mt < 4; ++mt)
                oacc[mt][dt] = __builtin_amdgcn_mfma_f32_16x16x32_bf16(pa[mt], vv, oacc[mt][dt], 0, 0, 0);
        }
    }

    // intra-wave denom reduction over quads
    #pragma unroll
    for (int mt = 0; mt < 4; ++mt) {
        psum[mt] += __shfl_xor(psum[mt], 16);
        psum[mt] += __shfl_xor(psum[mt], 32);
    }

    __syncthreads();   // all K/V/P reads done -> overlay is safe
    if (wave > 0) {
        float* rb = Red + (wave - 1) * 4096;
        #pragma unroll
        for (int mt = 0; mt < 4; ++mt)
            #pragma unroll
            for (int dt = 0; dt < 4; ++dt)
                *reinterpret_cast<floatx4*>(&rb[((mt * 4 + dt) * 64 + lane) * 4]) = oacc[mt][dt];
        if (lane < 16) {
            #pragma unroll
            for (int mt = 0; mt < 4; ++mt)
                Dred[((wave - 1) * 4 + mt) * 16 + l15] = psum[mt];
        }
    }
    __syncthreads();
    if (wave == 0) {
        #pragma unroll
        for (int w = 0; w < 3; ++w) {
            const float* rb = Red + w * 4096;
            #pragma unroll
            for (int mt = 0; mt < 4; ++mt) {
                #pragma unroll
                for (int dt = 0; dt < 4; ++dt) {
                    floatx4 t = *reinterpret_cast<const floatx4*>(&rb[((mt * 4 + dt) * 64 + lane) * 4]);
                    oacc[mt][dt][0] += t[0];
                    oacc[mt][dt][1] += t[1];
                    oacc[mt][dt][2] += t[2];
                    oacc[mt][dt][3] += t[3];
                }
                psum[mt] += Dred[(w * 4 + mt) * 16 + l15];
            }
        }
        #pragma unroll
        for (int mt = 0; mt < 4; ++mt) {
            float lr[4];
            #pragma unroll
            for (int r = 0; r < 4; ++r)
                lr[r] = __shfl(psum[mt], 4 * quad + r);
            #pragma unroll
            for (int dt = 0; dt < 4; ++dt)
                #pragma unroll
                for (int r = 0; r < 4; ++r)
                    AO[(size_t)(q0 + 16 * mt + 4 * quad + r) * kD + h * kHD + 16 * dt + l15] =
                        f2b(oacc[mt][dt][r] / lr[r]);
        }
    }
}

extern "C" void kernel_launch(void* const* d_in, const int* in_sizes, int n_in,
                              void* d_out, int out_size, void* d_ws, size_t ws_size,
                              hipStream_t stream)
{
    const float* x     = (const float*)d_in[0];  // (4096, 768) fp32
    const float* W_qkv = (const float*)d_in[1];  // (768, 2304) fp32
    const float* W_out = (const float*)d_in[2];  // (768, 768)  fp32
    const float* b_out = (const float*)d_in[3];  // (768,)      fp32
    float* out = (float*)d_out;                  // (4096, 768) fp32

    const size_t HNHD = (size_t)kH * kN * kHD;   // 3,145,728 shorts per tensor
    short* Qh    = (short*)d_ws;                 // [H][N][64]
    short* Kh    = Qh + HNHD;
    short* Vt    = Kh + HNHD;                    // [H][64][N]
    short* Xb    = Vt + HNHD;                    // x bf16 [N][768]; reused as AO
    short* WqkvT = Xb + (size_t)kN * kD;         // [2304][768]
    short* WoutT = WqkvT + (size_t)k3D * kD;     // [768][768]
    short* AO    = Xb;                           // overlay: Xb dead after QKV gemm
    (void)in_sizes; (void)n_in; (void)out_size; (void)ws_size;

    // 0) fused conversions/transposes
    prep<<<dim3(kBlkX + kBlkWq + kBlkWo), dim3(256), 0, stream>>>(
        x, W_qkv, W_out, Xb, WqkvT, WoutT);

    // 1) QKV projection + head scatter: 64x128 tile -> 1152 blocks (4.5/CU)
    gemm_qkv<<<dim3(kN / 64, k3D / 128), dim3(256), 0, stream>>>(
        Xb, WqkvT, Qh, Kh, Vt);
    // 2) flash attention
    attn<<<dim3(kN / 64, kH), dim3(256), 0, stream>>>(Qh, Kh, Vt, AO);
    // 3) output projection + bias: 64x64 tile -> 768 blocks (3/CU)
    gemm_out<<<dim3(kN / 64, kD / 64), dim3(256), 0, stream>>>(
        AO, WoutT, b_out, out);
}